// Round 8
// baseline (3644.497 us; speedup 1.0000x reference)
//
#include <hip/hip_runtime.h>

// 2-layer GRU, B=512 T=2048 IN=16 H=128 OUT=8.
// 32 WGs x 512 threads (8 waves, 2/SIMD). Waves 0-3 = layer-0 domain,
// waves 4-7 = layer-1 domain. NO per-tick s_barrier: domains free-run,
// synced by LDS progress words + 4-deep h0/h1 ring buffers (L0 may lead
// L1 by up to 3 ticks). SIMD k hosts one L0 + one L1 wave at different
// ticks -> MFMA/VALU/trans issue interleaves across waves continuously.
// Weights in regs as f16 A-frags (union by role, ~192 regs L1 / ~120 L0);
// Wout frags in LDS (keeps wave-7 peak = other L1 waves). Biases via LDS.
// Transposed MFMA: A=weights, B=h/x, D rows=hidden, cols=batch.

typedef unsigned int  uint;
typedef unsigned short ushort;
typedef _Float16 v8h __attribute__((ext_vector_type(8)));
typedef float    v4f __attribute__((ext_vector_type(4)));
typedef uint     v2u __attribute__((ext_vector_type(2)));

#define Tq   2048
#define INq  16
#define Hq   128
#define OUTq 8

#define MFMA(a,b,c) __builtin_amdgcn_mfma_f32_16x16x32_f16((a),(b),(c),0,0,0)

__device__ __forceinline__ float sigm(float x){
  return __builtin_amdgcn_rcpf(1.0f + __expf(-x));
}
__device__ __forceinline__ float tanh_f(float x){
  return 1.0f - 2.0f*__builtin_amdgcn_rcpf(__expf(2.0f*x) + 1.0f);
}
__device__ __forceinline__ uint packh2(float lo, float hi){
  _Float16 a=(_Float16)lo, b=(_Float16)hi;
  return (uint)__builtin_bit_cast(ushort,a) | ((uint)__builtin_bit_cast(ushort,b)<<16);
}
// wait until min(pa[0..3]) >= ta && min(pb[0..3]) >= tb
__device__ __forceinline__ void spin2(volatile int* pa, int ta,
                                      volatile int* pb, int tb){
  for(;;){
    int m0 = min(min(pa[0],pa[1]),min(pa[2],pa[3]));
    int m1 = min(min(pb[0],pb[1]),min(pb[2],pb[3]));
    if (m0 >= ta && m1 >= tb) break;
    __builtin_amdgcn_s_sleep(1);
  }
  __builtin_amdgcn_sched_barrier(0);
}
#define PUBLISH(arr, idx, val) do {                          \
  asm volatile("s_waitcnt lgkmcnt(0)" ::: "memory");         \
  __builtin_amdgcn_sched_barrier(0);                         \
  ((volatile int*)(arr))[idx] = (val);                       \
  __builtin_amdgcn_sched_barrier(0);                         \
} while(0)

__global__ __launch_bounds__(512,2) void gru2_kernel(
    const float* __restrict__ x,
    const float* __restrict__ Wih0, const float* __restrict__ Whh0,
    const float* __restrict__ bih0, const float* __restrict__ bhh0,
    const float* __restrict__ Wih1, const float* __restrict__ Whh1,
    const float* __restrict__ bih1, const float* __restrict__ bhh1,
    const float* __restrict__ Wout, const float* __restrict__ bout,
    float* __restrict__ out)
{
  const int tid  = threadIdx.x;
  const int lane = tid & 63;
  const int w    = tid >> 6;        // wave 0..7
  const int wl   = w & 3;           // slice index within role
  const bool isL0 = (w < 4);
  const int nb   = lane & 15;       // batch col
  const int bg   = lane >> 4;       // k-group / D row-group
  const int b0   = blockIdx.x * 16;

  __shared__ __align__(16) _Float16 hA0[4][2048];  // ring: h0(t) in slot t&3
  __shared__ __align__(16) _Float16 hA1[4][2048];  // ring: h1(t) in slot t&3
  __shared__ __align__(16) float    bl[1024];      // 8 x 128 bias table
  __shared__ __align__(16) _Float16 w3l[2048];     // Wout frags [ks][lane][8]
  __shared__ int prog0[4], prog1[4];

  for (int i=tid; i<4096; i+=512){ ((uint*)hA0)[i]=0u; ((uint*)hA1)[i]=0u; }
  for (int i=tid; i<1024; i+=512){
    const int k=i>>7, h=i&127; float v;
    if      (k==0) v = bih0[h]       + bhh0[h];
    else if (k==1) v = bih0[128+h]   + bhh0[128+h];
    else if (k==2) v = bih0[256+h];
    else if (k==3) v = bhh0[256+h];
    else if (k==4) v = bih1[h]       + bhh1[h];
    else if (k==5) v = bih1[128+h]   + bhh1[128+h];
    else if (k==6) v = bih1[256+h];
    else           v = bhh1[256+h];
    bl[i]=v;
  }
  if (tid < 4){ prog0[tid]=0; prog1[tid]=0; }

  // x prefetch (L0 waves), 1-deep
  const float* xrow = x + (size_t)(b0+nb)*Tq*INq;
  float4 xfa, xfb;
  if (isL0 && bg < 2){
    xfa = *(const float4*)(xrow + bg*8);
    xfb = *(const float4*)(xrow + bg*8 + 4);
  }

  // -------- weight fragments (union by role) --------
  v8h W1[2][3][4], W2[2][3][4];
  #pragma unroll
  for (int ta=0; ta<2; ++ta){
    const int R = 32*wl + 16*ta + nb;
    #pragma unroll
    for (int g=0; g<3; ++g){
      const int r = g*Hq + R;
      #pragma unroll
      for (int ks=0; ks<4; ++ks){
        const float* p1 = isL0 ? &Whh0[r*Hq + ks*32 + bg*8]
                               : &Wih1[r*Hq + ks*32 + bg*8];
        v8h a;
        #pragma unroll
        for (int e=0;e<8;++e) a[e]=(_Float16)p1[e];
        W1[ta][g][ks]=a;
      }
      if (isL0){
        v8h vx;
        #pragma unroll
        for (int e=0;e<8;++e) vx[e]=(_Float16)0.f;
        if (bg < 2){
          const float* p = &Wih0[r*INq + bg*8];
          #pragma unroll
          for (int e=0;e<8;++e) vx[e]=(_Float16)p[e];
        }
        W2[ta][g][0]=vx;
      } else {
        #pragma unroll
        for (int ks=0; ks<4; ++ks){
          const float* p2 = &Whh1[r*Hq + ks*32 + bg*8];
          v8h c;
          #pragma unroll
          for (int e=0;e<8;++e) c[e]=(_Float16)p2[e];
          W2[ta][g][ks]=c;
        }
      }
    }
  }
  if (w == 7){                        // Wout frags -> LDS
    #pragma unroll
    for (int ks=0; ks<4; ++ks){
      v8h v;
      #pragma unroll
      for (int e=0;e<8;++e) v[e]=(_Float16)0.f;
      if (nb < OUTq){
        const float* p = &Wout[nb*Hq + ks*32 + bg*8];
        #pragma unroll
        for (int e=0;e<8;++e) v[e]=(_Float16)p[e];
      }
      *(v8h*)&w3l[ks*512 + lane*8] = v;
    }
  }
  v4f bo4 = {0.f,0.f,0.f,0.f};
  if (bg < 2) bo4 = *(const v4f*)(bout + bg*4);
  const v4f zf = {0.f,0.f,0.f,0.f};

  float hs[2][4] = {{0,0,0,0},{0,0,0,0}};   // h0 (L0) or h1 (L1) state

  int rb[4];
  #pragma unroll
  for (int ks=0; ks<4; ++ks) rb[ks] = nb*128 + ((ks*4+bg) ^ nb)*8;
  const int wof0 = nb*128 + (((4*wl + 0 + (bg>>1)) ^ nb))*8 + (bg&1)*4;
  const int wof1 = nb*128 + (((4*wl + 2 + (bg>>1)) ^ nb))*8 + (bg&1)*4;

  __syncthreads();    // last whole-WG barrier (init done)

  if (isL0){
    // =========== layer-0 domain: tick t computes h0(t) ===========
    for (int t=0; t<Tq; ++t){
      // need: all L0 done t-1; backpressure: L1 done t-4 (overwrite h0(t-4))
      spin2(prog0, t, prog1, t-3);

      v8h ax;
      #pragma unroll
      for (int e=0;e<8;++e) ax[e]=(_Float16)0.f;
      if (bg < 2){
        ax[0]=(_Float16)xfa.x; ax[1]=(_Float16)xfa.y; ax[2]=(_Float16)xfa.z; ax[3]=(_Float16)xfa.w;
        ax[4]=(_Float16)xfb.x; ax[5]=(_Float16)xfb.y; ax[6]=(_Float16)xfb.z; ax[7]=(_Float16)xfb.w;
        int tn = t+1; if (tn > Tq-1) tn = Tq-1;
        xfa = *(const float4*)(xrow + tn*INq + bg*8);
        xfb = *(const float4*)(xrow + tn*INq + bg*8 + 4);
      }
      v8h a0k[4];
      #pragma unroll
      for (int ks=0; ks<4; ++ks) a0k[ks] = *(const v8h*)&hA0[(t-1)&3][rb[ks]];
      #pragma unroll
      for (int ta=0; ta<2; ++ta){
        const int hb4 = 32*wl + 16*ta + bg*4;
        v4f aR  = *(const v4f*)&bl[0*128+hb4];
        v4f aZ  = *(const v4f*)&bl[1*128+hb4];
        v4f aNX = *(const v4f*)&bl[2*128+hb4];
        v4f aNH = *(const v4f*)&bl[3*128+hb4];
        aR  = MFMA(W2[ta][0][0], ax, aR);
        aZ  = MFMA(W2[ta][1][0], ax, aZ);
        aNX = MFMA(W2[ta][2][0], ax, aNX);
        #pragma unroll
        for (int ks=0; ks<4; ++ks){
          aR  = MFMA(W1[ta][0][ks], a0k[ks], aR);
          aZ  = MFMA(W1[ta][1][ks], a0k[ks], aZ);
          aNH = MFMA(W1[ta][2][ks], a0k[ks], aNH);
        }
        float hn[4];
        #pragma unroll
        for (int j=0;j<4;++j){
          float r = sigm(aR[j]);
          float z = sigm(aZ[j]);
          float n = tanh_f(aNX[j] + r*aNH[j]);
          float h = n + z*(hs[ta][j]-n);
          hs[ta][j]=h; hn[j]=h;
        }
        v2u pk; pk[0]=packh2(hn[0],hn[1]); pk[1]=packh2(hn[2],hn[3]);
        *(v2u*)&hA0[t&3][ta ? wof1 : wof0] = pk;
      }
      PUBLISH(prog0, wl, t+1);
    }
  } else {
    // =========== layer-1 domain: tick t computes h1(t) ===========
    for (int t=0; t<Tq; ++t){
      // need: h0(t) ready (all L0 done t); all L1 done t-1
      spin2(prog0, t+1, prog1, t);

      v8h a0k[4];
      #pragma unroll
      for (int ks=0; ks<4; ++ks) a0k[ks] = *(const v8h*)&hA0[t&3][rb[ks]];
      #pragma unroll
      for (int ta=0; ta<2; ++ta){
        const int hb4 = 32*wl + 16*ta + bg*4;
        v4f cR  = *(const v4f*)&bl[4*128+hb4];
        v4f cZ  = *(const v4f*)&bl[5*128+hb4];
        v4f cNX = *(const v4f*)&bl[6*128+hb4];
        v4f cNH = *(const v4f*)&bl[7*128+hb4];
        #pragma unroll
        for (int ks=0; ks<4; ++ks){
          v8h a1 = *(const v8h*)&hA1[(t-1)&3][rb[ks]];
          cR  = MFMA(W1[ta][0][ks], a0k[ks], cR);
          cZ  = MFMA(W1[ta][1][ks], a0k[ks], cZ);
          cNX = MFMA(W1[ta][2][ks], a0k[ks], cNX);
          cR  = MFMA(W2[ta][0][ks], a1, cR);
          cZ  = MFMA(W2[ta][1][ks], a1, cZ);
          cNH = MFMA(W2[ta][2][ks], a1, cNH);
        }
        float hn[4];
        #pragma unroll
        for (int j=0;j<4;++j){
          float r = sigm(cR[j]);
          float z = sigm(cZ[j]);
          float n = tanh_f(cNX[j] + r*cNH[j]);
          float h = n + z*(hs[ta][j]-n);
          hs[ta][j]=h; hn[j]=h;
        }
        v2u pk; pk[0]=packh2(hn[0],hn[1]); pk[1]=packh2(hn[2],hn[3]);
        *(v2u*)&hA1[t&3][ta ? wof1 : wof0] = pk;
      }
      PUBLISH(prog1, wl, t+1);
      // out(t-1) on wave 7, AFTER publishing (doesn't block other L1 waves).
      // Reads hA1[(t-1)&3] (ready: prog1 >= t) and w3l frags.
      if (w == 7 && t >= 1){
        v4f oac = zf;
        #pragma unroll
        for (int ks=0; ks<4; ++ks){
          v8h a1 = *(const v8h*)&hA1[(t-1)&3][rb[ks]];
          v8h wf = *(const v8h*)&w3l[ks*512 + lane*8];
          oac = MFMA(wf, a1, oac);
        }
        if (bg < 2){
          float4 o;
          o.x=oac[0]+bo4[0]; o.y=oac[1]+bo4[1]; o.z=oac[2]+bo4[2]; o.w=oac[3]+bo4[3];
          *(float4*)&out[((size_t)(b0+nb)*Tq + (t-1))*OUTq + bg*4] = o;
        }
      }
    }
    // epilogue: out(Tq-1) once all L1 waves published tick Tq-1
    if (w == 7){
      spin2(prog1, Tq, prog1, Tq);
      v4f oac = zf;
      #pragma unroll
      for (int ks=0; ks<4; ++ks){
        v8h a1 = *(const v8h*)&hA1[(Tq-1)&3][rb[ks]];
        v8h wf = *(const v8h*)&w3l[ks*512 + lane*8];
        oac = MFMA(wf, a1, oac);
      }
      if (bg < 2){
        float4 o;
        o.x=oac[0]+bo4[0]; o.y=oac[1]+bo4[1]; o.z=oac[2]+bo4[2]; o.w=oac[3]+bo4[3];
        *(float4*)&out[((size_t)(b0+nb)*Tq + (Tq-1))*OUTq + bg*4] = o;
      }
    }
  }
}

extern "C" void kernel_launch(void* const* d_in, const int* in_sizes, int n_in,
                              void* d_out, int out_size, void* d_ws, size_t ws_size,
                              hipStream_t stream) {
  const float* x    = (const float*)d_in[0];
  const float* Wih0 = (const float*)d_in[1];
  const float* Whh0 = (const float*)d_in[2];
  const float* bih0 = (const float*)d_in[3];
  const float* bhh0 = (const float*)d_in[4];
  const float* Wih1 = (const float*)d_in[5];
  const float* Whh1 = (const float*)d_in[6];
  const float* bih1 = (const float*)d_in[7];
  const float* bhh1 = (const float*)d_in[8];
  const float* Wout = (const float*)d_in[9];
  const float* bo   = (const float*)d_in[10];
  gru2_kernel<<<dim3(32), dim3(512), 0, stream>>>(
      x, Wih0, Whh0, bih0, bhh0, Wih1, Whh1, bih1, bhh1, Wout, bo,
      (float*)d_out);
}